// Round 10
// baseline (76.822 us; speedup 1.0000x reference)
//
#include <hip/hip_runtime.h>
#include <hip/hip_bf16.h>
#include <math.h>

// out[n] = -EPS * logsumexp_m( lp[m] + (pot[m] - (x_n - pos_m)^2 / 2) / EPS )
//
// Validated reductions (R5-R8, absmax 0.00195 vs threshold 0.0787, exact
// across rounds):
//  1. softmin -> max (error <= eps*ln(M) = 0.0097, measured ~0.002)
//  2. drop eps*lse(logprob) const (~1e-6)
//  3. exact upper-envelope pruning: line m is dominated on |x| <= XB iff
//     exists m' with D[m'] - XB*|A[m']-A[m]| >= D[m] + MARGIN. Removing
//     dominated lines cannot change max_m(A*x+D) for |x| <= XB. Window
//     limiting only ADDS survivors (still exact).
//
//   out[n] = 0.5*x^2 - max_m( A[m]*x + D[m] ),
//   A[m] = pos[m],  D[m] = pot[m] + EPS*logprob[m] - 0.5*pos[m]^2
//
// R9 structure (3 -> 2 dispatches, no atomics, no init kernel):
//   P: 256 blocks x 256 thr. Block b prunes m in [b*64, b*64+64) against a
//      +-128 window; wave-0 ballot-compacts survivors to list[b*64..] and
//      writes cnts[b]. Everything written every call -> poison-safe.
//   E: 64 blocks x 256 thr. Prefix-sum cnts, gather survivors to LDS,
//      each thread scans all survivors (broadcast ds_read_b128) for its own
//      output. Uniform fallback to segmented global scan if n > 8192.

#define M_SUPPORT 16384
#define N_BATCH   16384
#define EPS_V  0.001f
#define XB     8.0f      // |x| bound: x ~ N(0,1); pos in [-1,7]
#define MARGIN 1e-5f
#define CAP    8192      // LDS survivor capacity in eval

__global__ __launch_bounds__(256) void prune_kernel(
    const float* __restrict__ pos, const float* __restrict__ logprob,
    const float* __restrict__ pot, int* __restrict__ cnts,
    float2* __restrict__ list)
{
    __shared__ float lA[320];
    __shared__ float lD[320];
    __shared__ int   sf[4][64];
    const int t    = threadIdx.x;
    const int lm   = t & 63;
    const int sub  = t >> 6;
    const int base = blockIdx.x * 64 - 128;

    // stage window [base, base+320): A = pos, D = pot + eps*logprob - p^2/2
    for (int i = t; i < 320; i += 256) {
        int idx = base + i;
        idx = idx < 0 ? 0 : (idx > M_SUPPORT - 1 ? M_SUPPORT - 1 : idx);
        const float p = pos[idx];
        lA[i] = p;
        lD[i] = pot[idx] + EPS_V * logprob[idx] - 0.5f * p * p;
    }
    __syncthreads();

    const float Am = lA[lm + 128];
    const float Dm = lD[lm + 128] + MARGIN;
    int dominated = 0;
    const int s0 = sub * 80;           // slice [s0, s0+80) of the 320-window
#pragma unroll 8
    for (int j = 0; j < 80; ++j) {
        const float a = lA[s0 + j];
        const float d = lD[s0 + j];
        // self-compare is safely false due to MARGIN
        dominated |= (d - XB * fabsf(a - Am) >= Dm) ? 1 : 0;
    }
    sf[sub][lm] = dominated;
    __syncthreads();

    if (t < 64) {   // wave 0: ballot-compact survivors, write count
        const int dom = sf[0][lm] | sf[1][lm] | sf[2][lm] | sf[3][lm];
        const unsigned long long mask = __ballot(!dom);
        if (!dom) {
            const int slot = (int)__popcll(mask & ((1ull << lm) - 1ull));
            list[blockIdx.x * 64 + slot] = make_float2(Am, lD[lm + 128]);
        }
        if (lm == 0) cnts[blockIdx.x] = (int)__popcll(mask);
    }
}

__global__ __launch_bounds__(256) void eval_kernel(
    const float* __restrict__ xs, const int* __restrict__ cnts,
    const float2* __restrict__ list, float* __restrict__ out)
{
    __shared__ __align__(16) float svraw[2 * CAP];   // survivor (A,D) pairs
    __shared__ int scnt[256];
    __shared__ int wt[4];
    float2* sv = (float2*)svraw;

    const int t    = threadIdx.x;
    const int lane = t & 63;
    const int w    = t >> 6;

    // ---- prefix-sum cnts[256] and gather survivors into LDS ----
    const int c = cnts[t];
    scnt[t] = c;
    int sc = c;
#pragma unroll
    for (int d = 1; d < 64; d <<= 1) {
        const int v = __shfl_up(sc, d);
        if (lane >= d) sc += v;
    }
    if (lane == 63) wt[w] = sc;
    __syncthreads();
    int off = 0;
    for (int k = 0; k < w; ++k) off += wt[k];
    const int excl = off + sc - c;
    for (int i = 0; i < c; ++i)
        if (excl + i < CAP) sv[excl + i] = list[t * 64 + i];
    const int n = wt[0] + wt[1] + wt[2] + wt[3];
    __syncthreads();

    // ---- each thread evaluates its own output over all survivors ----
    const int nidx = blockIdx.x * 256 + t;
    const float x = xs[nidx];
    float acc = -INFINITY;

    if (n <= CAP) {
        int i = 0;
        for (; i + 2 <= n; i += 2) {      // ds_read_b128: 2 survivors/read
            const float4 q = *(const float4*)&sv[i];
            acc = fmaxf(fmaxf(acc, fmaf(q.x, x, q.y)), fmaf(q.z, x, q.w));
        }
        if (i < n) {
            const float2 q = sv[i];
            acc = fmaxf(acc, fmaf(q.x, x, q.y));
        }
    } else {
        // pathological fallback (never triggers on the fixed input seed):
        // segmented scan straight from the global list — slow but exact.
        for (int b = 0; b < 256; ++b) {
            const int nb = scnt[b];
            for (int i = 0; i < nb; ++i) {
                const float2 q = list[b * 64 + i];
                acc = fmaxf(acc, fmaf(q.x, x, q.y));
            }
        }
    }

    out[nidx] = 0.5f * x * x - acc;
}

extern "C" void kernel_launch(void* const* d_in, const int* in_sizes, int n_in,
                              void* d_out, int out_size, void* d_ws, size_t ws_size,
                              hipStream_t stream)
{
    const float* x       = (const float*)d_in[0];
    const float* pos     = (const float*)d_in[1];
    const float* logprob = (const float*)d_in[2];
    const float* pot     = (const float*)d_in[3];

    int*    cnts = (int*)d_ws;                          // 256 ints
    float2* list = (float2*)((char*)d_ws + 1024);       // 16384 float2 max
    float*  outp = (float*)d_out;

    hipLaunchKernelGGL(prune_kernel, dim3(M_SUPPORT / 64), dim3(256), 0, stream,
                       pos, logprob, pot, cnts, list);
    hipLaunchKernelGGL(eval_kernel, dim3(N_BATCH / 256), dim3(256), 0, stream,
                       x, cnts, list, outp);
}

// Round 11
// 70.300 us; speedup vs baseline: 1.0928x; 1.0928x over previous
//
#include <hip/hip_runtime.h>
#include <hip/hip_bf16.h>
#include <math.h>

// out[n] = -EPS * logsumexp_m( lp[m] + (pot[m] - (x_n - pos_m)^2 / 2) / EPS )
//
// Validated reductions (R5-R8, absmax 0.00195 vs threshold 0.0787):
//  1. softmin -> max (error <= eps*ln(M) = 0.0097, measured ~0.002)
//  2. drop eps*lse(logprob) const (~1e-6)
//  3. exact upper-envelope pruning: line m is dominated on |x| <= XB iff
//     exists m' with D[m'] - XB*|A[m']-A[m]| >= D[m] + MARGIN. Removing
//     dominated lines cannot change max_m(A*x+D) for |x| <= XB. Window
//     limiting only ADDS survivors (still exact).
//
//   out[n] = 0.5*x^2 - max_m( A[m]*x + D[m] ),
//   A[m] = pos[m],  D[m] = pot[m] + EPS*logprob[m] - 0.5*pos[m]^2
//
// R11 = R8 verbatim (best-measured: 69.9 us). R10's 2-dispatch restructure
// measured worse (76.8): 64-block grid + serial per-thread max chain lost
// more than the saved launch gap. Keeping: 3 dispatches, 512-block eval,
// coalesced per-lane survivor loads, 32 independent max chains/thread.
//
// ws layout: [0..3] cnt (int), +16: survivor float2 (A,D) list (<=16384).

#define M_SUPPORT 16384
#define N_BATCH   16384
#define EPS_V  0.001f
#define XB     8.0f      // |x| bound: x ~ N(0,1), max|x| ~ 4.1; pos in [-1,7]
#define MARGIN 1e-5f

__global__ __launch_bounds__(64) void zero_cnt_kernel(int* __restrict__ cnt) {
    if (threadIdx.x == 0) cnt[0] = 0;
}

// 256 blocks x 256 threads; block owns m in [blk*64, blk*64+64).
// Thread (sub, lm): sub = t>>6 checks a 128-wide slice of the +-256 window.
__global__ __launch_bounds__(256) void prune_kernel(
    const float* __restrict__ pos, const float* __restrict__ logprob,
    const float* __restrict__ pot, int* __restrict__ cnt,
    float2* __restrict__ list)
{
    __shared__ float lA[576];
    __shared__ float lD[576];
    __shared__ int   sf[4][64];
    const int t    = threadIdx.x;
    const int lm   = t & 63;
    const int sub  = t >> 6;
    const int base = blockIdx.x * 64 - 256;

    // stage window [base, base+576): A = pos, D = pot + eps*logprob - p^2/2
    for (int i = t; i < 576; i += 256) {
        int idx = base + i;
        idx = idx < 0 ? 0 : (idx > M_SUPPORT - 1 ? M_SUPPORT - 1 : idx);
        const float p = pos[idx];
        lA[i] = p;
        lD[i] = pot[idx] + EPS_V * logprob[idx] - 0.5f * p * p;
    }
    __syncthreads();

    const float Am = lA[lm + 256];
    const float Dm = lD[lm + 256] + MARGIN;
    int dominated = 0;
    const int s0 = lm + sub * 128;   // slice [s0, s0+128) of the LDS window
#pragma unroll 8
    for (int j = 0; j < 128; ++j) {
        const float a = lA[s0 + j];
        const float d = lD[s0 + j];
        // self-compare (a==Am, d==Dm-MARGIN) is safely false due to MARGIN
        dominated |= (d - XB * fabsf(a - Am) >= Dm) ? 1 : 0;
    }
    sf[sub][lm] = dominated;
    __syncthreads();

    if (sub == 0) {
        if (!(sf[0][lm] | sf[1][lm] | sf[2][lm] | sf[3][lm])) {
            const int slot = atomicAdd(cnt, 1);          // order irrelevant
            list[slot] = make_float2(Am, lD[lm + 256]);
        }
    }
}

// 512 blocks x 256 threads; block owns 32 outputs. x_j broadcast via
// v_readlane -> SGPRs; acc[32] in VGPRs; survivors scanned coalesced.
// Butterfly reduce (validated R5-R8): after 5 reg-halving levels +
// shfl_xor(32), lane l holds the wave max for output j = bitrev5(l&31).
__global__ __launch_bounds__(256) void eval_kernel(
    const float* __restrict__ xs, const int* __restrict__ cnt,
    const float2* __restrict__ list, float* __restrict__ out)
{
    const int t    = threadIdx.x;
    const int lane = t & 63;
    const int w    = t >> 6;
    const int base = blockIdx.x * 32;
    __shared__ float sm[4][32];

    const int n = *cnt;   // wave-uniform scalar load

    const float xv = xs[base + (lane & 31)];
    float xj[32];
#pragma unroll
    for (int j = 0; j < 32; ++j)
        xj[j] = __int_as_float(__builtin_amdgcn_readlane(__float_as_int(xv), j));

    float acc[32];
#pragma unroll
    for (int j = 0; j < 32; ++j) acc[j] = -INFINITY;

    for (int i = w * 64 + lane; i < n; i += 256) {
        const float2 ad = list[i];
#pragma unroll
        for (int j = 0; j < 32; ++j)
            acc[j] = fmaxf(acc[j], fmaf(ad.x, xj[j], ad.y));
    }

#pragma unroll
    for (int s5 = 0; s5 < 5; ++s5) {
        const int d = 1 << s5;
        const int h = 16 >> s5;
#pragma unroll
        for (int i = 0; i < h; ++i) {
            const float lo = acc[i], hi = acc[i + h];
            const float sent = (lane & d) ? lo : hi;
            const float got  = __shfl_xor(sent, d);
            acc[i] = (lane & d) ? fmaxf(hi, got) : fmaxf(lo, got);
        }
    }
    const float v = fmaxf(acc[0], __shfl_xor(acc[0], 32));
    const int j = (int)(__brev((unsigned)(lane & 31)) >> 27);  // bitrev5
    if (lane < 32) sm[w][j] = v;
    __syncthreads();

    if (t < 32) {
        float M = sm[0][t];
#pragma unroll
        for (int k = 1; k < 4; ++k) M = fmaxf(M, sm[k][t]);
        const float x = xs[base + t];
        out[base + t] = 0.5f * x * x - M;
    }
}

extern "C" void kernel_launch(void* const* d_in, const int* in_sizes, int n_in,
                              void* d_out, int out_size, void* d_ws, size_t ws_size,
                              hipStream_t stream)
{
    const float* x       = (const float*)d_in[0];
    const float* pos     = (const float*)d_in[1];
    const float* logprob = (const float*)d_in[2];
    const float* pot     = (const float*)d_in[3];

    int*    cnt  = (int*)d_ws;
    float2* list = (float2*)((char*)d_ws + 16);
    float*  outp = (float*)d_out;

    hipLaunchKernelGGL(zero_cnt_kernel, dim3(1), dim3(64), 0, stream, cnt);
    hipLaunchKernelGGL(prune_kernel, dim3(M_SUPPORT / 64), dim3(256), 0, stream,
                       pos, logprob, pot, cnt, list);
    hipLaunchKernelGGL(eval_kernel, dim3(N_BATCH / 32), dim3(256), 0, stream,
                       x, cnt, list, outp);
}